// Round 1
// baseline (7272.295 us; speedup 1.0000x reference)
//
#include <hip/hip_runtime.h>
#include <stdint.h>
#include <stddef.h>

// Problem constants
#define B_   32
#define S_   512
#define D_   768
#define H_   1024
#define NF_  50
#define NR_  35
#define NWG  128      // 64 WGs per cell, 16 hidden units each
#define WGS  256

// ws layout (bytes):
//   [24576, 40960)     itBuf tagged: 64 rows x 32 cols of b64 (f32 value | u32 tag<<32), single buffer
//   [65536, 1458176)   pf tagged: F 32*64*50 b64, then R 32*64*35 b64, single buffer
//   [1703936, ...)     xbf
#define IT_OFF    24576
#define PF_OFF    65536
#define PF_F_B64  102400            // 32*64*50 b64 slots
#define PF_R_B64  71680             // 32*64*35 b64 slots
#define XBF_OFF   1703936

typedef __attribute__((ext_vector_type(8))) short sh8;   // 8 x bf16 MFMA operand
typedef __attribute__((ext_vector_type(4))) float f4;
typedef __attribute__((ext_vector_type(2))) float f2v;
typedef __attribute__((ext_vector_type(4))) unsigned int u4x;
typedef unsigned long long u64;

__device__ __forceinline__ unsigned short f2bf(float f) {
  unsigned int u = __float_as_uint(f);
  u += 0x7fffu + ((u >> 16) & 1u);
  return (unsigned short)(u >> 16);
}

__device__ __forceinline__ sh8 cvt8(const float* __restrict__ p) {
  f4 av = *(const f4*)p;
  f4 bv = *(const f4*)(p + 4);
  union { sh8 s; unsigned short us[8]; } r;
  r.us[0] = f2bf(av[0]); r.us[1] = f2bf(av[1]); r.us[2] = f2bf(av[2]); r.us[3] = f2bf(av[3]);
  r.us[4] = f2bf(bv[0]); r.us[5] = f2bf(bv[1]); r.us[6] = f2bf(bv[2]); r.us[7] = f2bf(bv[3]);
  return r.s;
}

__device__ __forceinline__ float sigm(float x) { return 1.f / (1.f + __expf(-x)); }

// tagged-b64 helpers: value in low 32, step tag in high 32 (single-copy atomic unit)
__device__ __forceinline__ u64 tagv(float v, unsigned t) {
  return (u64)__float_as_uint(v) | ((u64)t << 32);
}
__device__ __forceinline__ float    valof(u64 p) { return __uint_as_float((unsigned)p); }
__device__ __forceinline__ unsigned tagof(u64 p) { return (unsigned)(p >> 32); }

// ---------------------------------------------------------------- init ws
// zero all tag words (tags live inside pf/itBuf b64s now): 16 KB + 1.39 MB
__global__ void init_ws(unsigned char* __restrict__ ws) {
  const int t = blockIdx.x * blockDim.x + threadIdx.x;
  const int stride = gridDim.x * blockDim.x;
  const u4x z = {0u, 0u, 0u, 0u};
  u4x* a = (u4x*)(ws + IT_OFF);             // 16384 B = 1024 chunks
  for (int i = t; i < 1024; i += stride) a[i] = z;
  u4x* b = (u4x*)(ws + PF_OFF);             // 1392640 B = 87040 chunks
  for (int i = t; i < 87040; i += stride) b[i] = z;
}

// ------------------------------------------------------- x fp32 -> bf16
__global__ void xcvt(const float* __restrict__ x, unsigned int* __restrict__ xb2, int npairs) {
  const int stride = gridDim.x * blockDim.x;
  for (int i = blockIdx.x * blockDim.x + threadIdx.x; i < npairs; i += stride) {
    f2v v = ((const f2v*)x)[i];
    xb2[i] = (unsigned int)f2bf(v[0]) | ((unsigned int)f2bf(v[1]) << 16);
  }
}

// ---------------------------------------------------------- persistent
__global__ __launch_bounds__(WGS, 1) void tpr_persist(
    const float* __restrict__ x, const unsigned short* __restrict__ xbf, int xmode,
    const float* __restrict__ WihF, const float* __restrict__ WhhF,
    const float* __restrict__ bihF, const float* __restrict__ bhhF,
    const float* __restrict__ WihR, const float* __restrict__ WhhR,
    const float* __restrict__ bihR, const float* __restrict__ bhhR,
    const float* __restrict__ WaFw, const float* __restrict__ WaFb,
    const float* __restrict__ WaRw, const float* __restrict__ WaRb,
    const float* __restrict__ Fw, const float* __restrict__ Rw,
    const float* __restrict__ scFp, const float* __restrict__ scRp,
    float* __restrict__ out0, unsigned char* __restrict__ ws)
{
  __shared__ __align__(16) unsigned short T_lds[32 * 1032];  // 66048 B
  __shared__ __align__(16) float part[4][32 * 69];           // 35328 B; reused as pf stage
  __shared__ float h_lds[32 * 16];
  __shared__ float itF_l[32 * 33];
  __shared__ float itR_l[32 * 33];
  __shared__ float Fw_l[32 * NF_];
  __shared__ float Rw_l[32 * NR_];
  __shared__ float Wa_l[NF_ * 17];
  __shared__ float red4[4][64];
  __shared__ float arow[64];
  __shared__ float bias_l[64];
  __shared__ float bF_l[NF_];
  __shared__ float bR_l[NR_];

  const int wg   = blockIdx.x;
  const int tid  = threadIdx.x;
  const int wave = tid >> 6;
  const int lane = tid & 63;
  const int n16  = lane & 15;
  const int quad = lane >> 4;
  const bool isF = wg < 64;
  const int wIdx = wg & 63;            // writer index within cell
  const int j0   = wIdx * 16;
  const float* Wih = isF ? WihF : WihR;
  const float* Whh = isF ? WhhF : WhhR;
  const float* bih = isF ? bihF : bihR;
  const float* bhh = isF ? bhhF : bhhR;
  const float* Wa  = isF ? WaFw : WaRw;
  const int NA  = isF ? NF_ : NR_;

  u64* itb = (u64*)(ws + IT_OFF);
  u64* pfF = (u64*)(ws + PF_OFF);
  u64* pfR = pfF + PF_F_B64;

  // ---- resident weight fragments: wave owns K-quarter; 4 gate n-tiles
  sh8 whhf[4][8];
  sh8 wihf[4][6];
  #pragma unroll
  for (int g = 0; g < 4; ++g) {
    const int row = g * 1024 + j0 + n16;
    #pragma unroll
    for (int ks = 0; ks < 8; ++ks)
      whhf[g][ks] = cvt8(Whh + (size_t)row * H_ + wave * 256 + ks * 32 + quad * 8);
    #pragma unroll
    for (int ks = 0; ks < 6; ++ks)
      wihf[g][ks] = cvt8(Wih + (size_t)row * D_ + wave * 192 + ks * 32 + quad * 8);
  }

  if (tid < 64) {
    const int row = (tid >> 4) * 1024 + j0 + (tid & 15);
    bias_l[tid] = bih[row] + bhh[row];
  }
  for (int i = tid; i < NA * 16; i += WGS)
    Wa_l[(i >> 4) * 17 + (i & 15)] = Wa[(size_t)(i >> 4) * H_ + j0 + (i & 15)];
  for (int i = tid; i < 32 * NF_; i += WGS) Fw_l[i] = Fw[i];
  for (int i = tid; i < 32 * NR_; i += WGS) Rw_l[i] = Rw[i];
  if (tid < NF_) bF_l[tid] = WaFb[tid];
  if (tid < NR_) bR_l[tid] = WaRb[tid];
  {
    u4x z = {0u, 0u, 0u, 0u};
    for (int i = tid; i < (32 * 1032) / 8; i += WGS) ((u4x*)T_lds)[i] = z;
  }
  const float sF = scFp[0];
  const float sR = scRp[0];
  float c0 = 0.f, c1 = 0.f;

  f4 xacc[2][4];
  const f4 fz = {0.f, 0.f, 0.f, 0.f};

  auto xpart = [&](int sx) {
    #pragma unroll
    for (int bt = 0; bt < 2; ++bt)
      #pragma unroll
      for (int g = 0; g < 4; ++g) xacc[bt][g] = fz;
    #pragma unroll
    for (int ks = 0; ks < 6; ++ks) {
      sh8 xa[2];
      #pragma unroll
      for (int bt = 0; bt < 2; ++bt) {
        const size_t off = ((size_t)(bt * 16 + n16) * S_ + sx) * D_ + wave * 192 + ks * 32 + quad * 8;
        if (xmode == 0) {
          union { u4x u; sh8 s; } t;
          t.u = *(const u4x*)(xbf + off);
          xa[bt] = t.s;
        } else {
          xa[bt] = cvt8(x + off);
        }
      }
      #pragma unroll
      for (int bt = 0; bt < 2; ++bt)
        #pragma unroll
        for (int g = 0; g < 4; ++g)
          xacc[bt][g] = __builtin_amdgcn_mfma_f32_16x16x32_bf16(xa[bt], wihf[g][ks], xacc[bt][g], 0, 0, 0);
    }
  };

  xpart(0);
  __syncthreads();

  float* out1 = out0 + (size_t)B_ * S_ * H_;
  float* out2 = out1 + (size_t)B_ * S_ * NF_;

  // reducers: F on wg 0..31 (batch=wg), R on wg 96..127 (batch=wg-96)
  const bool isRed = (wg < 32) || (wg >= 96);
  const int  redB  = (wg < 32) ? wg : wg - 96;
  const bool redF  = (wg < 32);
  const int  redJ  = (redF ? 0 : 32) + redB;     // itBuf row index

  for (int s = 0; s < S_; ++s) {
    const unsigned int stag = (unsigned int)(s + 1);

    // ---- 1. gates = xacc + T(s-1) @ Whh^T
    f4 acc[2][4];
    #pragma unroll
    for (int bt = 0; bt < 2; ++bt)
      #pragma unroll
      for (int g = 0; g < 4; ++g) acc[bt][g] = xacc[bt][g];
    if (s > 0) {
      #pragma unroll
      for (int ks = 0; ks < 8; ++ks) {
        sh8 aT[2];
        #pragma unroll
        for (int bt = 0; bt < 2; ++bt)
          aT[bt] = *(const sh8*)&T_lds[(bt * 16 + n16) * 1032 + wave * 256 + ks * 32 + quad * 8];
        #pragma unroll
        for (int bt = 0; bt < 2; ++bt)
          #pragma unroll
          for (int g = 0; g < 4; ++g)
            acc[bt][g] = __builtin_amdgcn_mfma_f32_16x16x32_bf16(aT[bt], whhf[g][ks], acc[bt][g], 0, 0, 0);
      }
    }
    #pragma unroll
    for (int bt = 0; bt < 2; ++bt)
      #pragma unroll
      for (int g = 0; g < 4; ++g)
        #pragma unroll
        for (int r = 0; r < 4; ++r)
          part[wave][(bt * 16 + quad * 4 + r) * 69 + g * 16 + n16] = acc[bt][g][r];
    __syncthreads();

    // ---- 2. cross-wave reduce -> nonlinearity -> c,h
    {
      const int b = tid >> 3;
      const int jb = (tid & 7) * 2;
      #pragma unroll
      for (int u = 0; u < 2; ++u) {
        const int jj = jb + u;
        float G[4];
        #pragma unroll
        for (int g = 0; g < 4; ++g) {
          const int n = g * 16 + jj;
          G[g] = bias_l[n] + part[0][b * 69 + n] + part[1][b * 69 + n]
                           + part[2][b * 69 + n] + part[3][b * 69 + n];
        }
        const float ig = sigm(G[0]);
        const float fg = sigm(G[1]);
        const float gg = tanhf(G[2]);
        const float og = sigm(G[3]);
        float& c = u ? c1 : c0;
        c = fg * c + ig * gg;
        h_lds[b * 16 + jj] = og * tanhf(c);
      }
    }
    __syncthreads();

    // ---- 3. partial logits -> tagged b64 pf stores (no drain, no tag line)
    if (isF) {
      for (int i = tid; i < 32 * NF_; i += WGS) {
        const int b = i / NF_, n = i - b * NF_;
        float v = 0.f;
        #pragma unroll
        for (int jj = 0; jj < 16; ++jj) v += h_lds[b * 16 + jj] * Wa_l[n * 17 + jj];
        __hip_atomic_store(&pfF[((size_t)b * 64 + wIdx) * NF_ + n], tagv(v, stag),
                           __ATOMIC_RELAXED, __HIP_MEMORY_SCOPE_AGENT);
      }
    } else {
      for (int i = tid; i < 32 * NR_; i += WGS) {
        const int b = i / NR_, n = i - b * NR_;
        float v = 0.f;
        #pragma unroll
        for (int jj = 0; jj < 16; ++jj) v += h_lds[b * 16 + jj] * Wa_l[n * 17 + jj];
        __hip_atomic_store(&pfR[((size_t)b * 64 + wIdx) * NR_ + n], tagv(v, stag),
                           __ATOMIC_RELAXED, __HIP_MEMORY_SCOPE_AGENT);
      }
    }

    // ---- 4. reducers: pipelined tagged gather -> reduce -> softmax -> items
    if (isRed) {
      float* stage = &part[0][0];
      if (redF) {
        const u64* src = pfF + (size_t)redB * 64 * NF_;
        unsigned sm = 0; int k = 0;
        for (int i = tid; i < 64 * NF_; i += WGS, ++k) {
          const u64 p = __hip_atomic_load(&src[i], __ATOMIC_RELAXED, __HIP_MEMORY_SCOPE_AGENT);
          stage[i] = valof(p);
          sm |= (tagof(p) != stag) ? (1u << k) : 0u;
        }
        while (sm) {
          __builtin_amdgcn_s_sleep(2);
          k = 0;
          for (int i = tid; i < 64 * NF_; i += WGS, ++k) if (sm & (1u << k)) {
            const u64 p = __hip_atomic_load(&src[i], __ATOMIC_RELAXED, __HIP_MEMORY_SCOPE_AGENT);
            if (tagof(p) == stag) { stage[i] = valof(p); sm &= ~(1u << k); }
          }
        }
      } else {
        const u64* src = pfR + (size_t)redB * 64 * NR_;
        unsigned sm = 0; int k = 0;
        for (int i = tid; i < 64 * NR_; i += WGS, ++k) {
          const u64 p = __hip_atomic_load(&src[i], __ATOMIC_RELAXED, __HIP_MEMORY_SCOPE_AGENT);
          stage[i] = valof(p);
          sm |= (tagof(p) != stag) ? (1u << k) : 0u;
        }
        while (sm) {
          __builtin_amdgcn_s_sleep(2);
          k = 0;
          for (int i = tid; i < 64 * NR_; i += WGS, ++k) if (sm & (1u << k)) {
            const u64 p = __hip_atomic_load(&src[i], __ATOMIC_RELAXED, __HIP_MEMORY_SCOPE_AGENT);
            if (tagof(p) == stag) { stage[i] = valof(p); sm &= ~(1u << k); }
          }
        }
      }
      __syncthreads();
      const int NAr = redF ? NF_ : NR_;
      // parallel partial reduce: wave w sums writer rows [w*16, w*16+16)
      {
        const float* stg = &part[0][0];
        const int n = (lane < NAr) ? lane : 0;
        float v = 0.f;
        #pragma unroll
        for (int w2 = 0; w2 < 16; ++w2) v += stg[(wave * 16 + w2) * NAr + n];
        red4[wave][lane] = v;
      }
      __syncthreads();
      if (wave == 0) {
        const int n = (lane < NAr) ? lane : 0;
        const float v = red4[0][lane] + red4[1][lane] + red4[2][lane] + red4[3][lane];
        const float* bA = redF ? bF_l : bR_l;
        float e = (lane < NAr) ? __expf(v + bA[n]) : 0.f;
        float ssum = e;
        #pragma unroll
        for (int off = 1; off < 64; off <<= 1) ssum += __shfl_xor(ssum, off, 64);
        const float a = e / ssum;
        if (lane < NAr) arow[lane] = a;
        if (lane < 32) {
          const float* WL = redF ? Fw_l : Rw_l;
          const float sc = redF ? sF : sR;
          float it = 0.f;
          for (int k = 0; k < NAr; ++k) it += arow[k] * WL[lane * NAr + k];
          it *= sc;
          // tagged publish: value+tag in one b64, no drain, no rtag line
          __hip_atomic_store(&itb[(size_t)redJ * 32 + lane], tagv(it, stag),
                             __ATOMIC_RELAXED, __HIP_MEMORY_SCOPE_AGENT);
        }
        // outputs AFTER the publish (off the critical path)
        if (lane < NAr) {
          float* outA = redF ? out1 : out2;
          outA[((size_t)redB * S_ + s) * NAr + lane] = a;
        }
      }
    }

    // ---- 5. overlap: next step's x-projection
    if (s + 1 < S_) xpart(s + 1);

    // ---- 6/7. gather itemF/itemR: pipelined tagged-data poll, stage to LDS
    {
      const u64* it64 = (const u64*)(ws + IT_OFF);
      unsigned sm = 0;
      #pragma unroll
      for (int k = 0; k < 8; ++k) {
        const int i = tid + k * WGS;
        const u64 p = __hip_atomic_load(&it64[i], __ATOMIC_RELAXED, __HIP_MEMORY_SCOPE_AGENT);
        const int row = i >> 5, c = i & 31;
        if (row < 32) itF_l[row * 33 + c] = valof(p);
        else          itR_l[(row - 32) * 33 + c] = valof(p);
        sm |= (tagof(p) != stag) ? (1u << k) : 0u;
      }
      while (sm) {
        __builtin_amdgcn_s_sleep(2);
        #pragma unroll
        for (int k = 0; k < 8; ++k) if (sm & (1u << k)) {
          const int i = tid + k * WGS;
          const u64 p = __hip_atomic_load(&it64[i], __ATOMIC_RELAXED, __HIP_MEMORY_SCOPE_AGENT);
          if (tagof(p) == stag) {
            const int row = i >> 5, c = i & 31;
            if (row < 32) itF_l[row * 33 + c] = valof(p);
            else          itR_l[(row - 32) * 33 + c] = valof(p);
            sm &= ~(1u << k);
          }
        }
      }
    }
    __syncthreads();

    // ---- 8. T(s) = outer(itemF,itemR) -> bf16 LDS ; out0 by wg 32..63
    {
      const int b = tid & 31;
      const int ds0 = (tid >> 5) * 4;
      #pragma unroll
      for (int dsb = 0; dsb < 4; ++dsb) {
        const int ds = ds0 + dsb;
        const float fv = itF_l[b * 33 + ds];
        union { unsigned short us[32]; u4x v[4]; } tmp;
        #pragma unroll
        for (int dr = 0; dr < 32; ++dr) tmp.us[dr] = f2bf(fv * itR_l[b * 33 + dr]);
        #pragma unroll
        for (int q = 0; q < 4; ++q)
          *(u4x*)&T_lds[b * 1032 + ds * 32 + q * 8] = tmp.v[q];
      }
    }
    if (wg >= 32 && wg < 64) {
      const int b = wg - 32;
      const int ds = tid >> 3, dr0 = (tid & 7) * 4;
      f4 v;
      #pragma unroll
      for (int q = 0; q < 4; ++q) v[q] = itF_l[b * 33 + ds] * itR_l[b * 33 + dr0 + q];
      *(f4*)&out0[((size_t)b * S_ + s) * H_ + tid * 4] = v;
    }
    __syncthreads();
  }
}

// ------------------------------------------------------------- launcher
extern "C" void kernel_launch(void* const* d_in, const int* in_sizes, int n_in,
                              void* d_out, int out_size, void* d_ws, size_t ws_size,
                              hipStream_t stream) {
  (void)in_sizes; (void)n_in; (void)out_size;
  const float* x    = (const float*)d_in[0];
  const float* WihF = (const float*)d_in[1];
  const float* WhhF = (const float*)d_in[2];
  const float* bihF = (const float*)d_in[3];
  const float* bhhF = (const float*)d_in[4];
  const float* WihR = (const float*)d_in[5];
  const float* WhhR = (const float*)d_in[6];
  const float* bihR = (const float*)d_in[7];
  const float* bihR2= (const float*)d_in[8];
  const float* WaFw = (const float*)d_in[9];
  const float* WaFb = (const float*)d_in[10];
  const float* WaRw = (const float*)d_in[11];
  const float* WaRb = (const float*)d_in[12];
  const float* Fw   = (const float*)d_in[13];
  const float* Rw   = (const float*)d_in[14];
  const float* scF  = (const float*)d_in[15];
  const float* scR  = (const float*)d_in[16];

  unsigned char* ws = (unsigned char*)d_ws;
  unsigned short* xbf = (unsigned short*)(ws + XBF_OFF);
  const size_t need = (size_t)XBF_OFF + (size_t)B_ * S_ * D_ * 2;
  const int xmode = (ws_size >= need) ? 0 : 1;

  init_ws<<<344, 256, 0, stream>>>(ws);
  if (xmode == 0)
    xcvt<<<2048, 256, 0, stream>>>(x, (unsigned int*)xbf, (B_ * S_ * D_) / 2);
  tpr_persist<<<NWG, WGS, 0, stream>>>(x, xbf, xmode,
      WihF, WhhF, bihF, bhhF, WihR, WhhR, bihR, bihR2,
      WaFw, WaFb, WaRw, WaRb, Fw, Rw, scF, scR,
      (float*)d_out, ws);
}